// Round 1
// baseline (956.914 us; speedup 1.0000x reference)
//
#include <hip/hip_runtime.h>
#include <math.h>

#define NB  32
#define NLQ 2048
#define NLK 2048
#define ND  128
#define KT  64
#define QT  64
#define SCALE 11.3137084989847603904f  /* sqrt(128) — bug kept: MULTIPLY by sqrt(dk) */

typedef float f32x4 __attribute__((ext_vector_type(4)));
typedef short s16x8 __attribute__((ext_vector_type(8)));

__device__ int g_maskflag;

static __device__ __forceinline__ unsigned short f2bf(float x) {
    unsigned int u = __float_as_uint(x);
    return (unsigned short)((u + 0x7FFFu + ((u >> 16) & 1u)) >> 16);
}
static __device__ __forceinline__ float bf2f(unsigned short b) {
    return __uint_as_float(((unsigned int)b) << 16);
}

#define SPLIT8(H, L, J, VAL) do { float _v = (VAL); unsigned short _hb = f2bf(_v); \
    (H)[J] = (short)_hb; (L)[J] = (short)f2bf(_v - bf2f(_hb)); } while (0)

__global__ void zero_flag_kernel() { if (threadIdx.x == 0) g_maskflag = 0; }

// Mask dtype probe: byte offsets ≡1 (mod 4) are 0 for int32/float32 layouts,
// ~10% nonzero for 1-byte bool layout. Samples first ~1MB (safe for both).
__global__ void detect_mask_kernel(const unsigned char* __restrict__ m) {
    unsigned int i = blockIdx.x * blockDim.x + threadIdx.x;
    if (m[(size_t)i * 4 + 1] != 0) atomicOr(&g_maskflag, 1);
}

__global__ void __launch_bounds__(256, 2)
attn_kernel(const float* __restrict__ Q, const float* __restrict__ K,
            const float* __restrict__ V, const unsigned char* __restrict__ Mb,
            float* __restrict__ Out)
{
    // LDS: all tiles XOR-swizzled with ((row&7)<<4) byte swizzle (G4) -> 2-way max on reads
    __shared__ unsigned short sKh[KT * ND];   // bf16 hi of K, [k][d]
    __shared__ unsigned short sKl[KT * ND];   // bf16 lo of K
    __shared__ unsigned short sVt[ND * KT];   // bf16 V transposed, [d][k]
    __shared__ unsigned short sP[4][16 * KT]; // per-wave P, [q][k]

    const int tid  = threadIdx.x;
    const int wave = tid >> 6;
    const int ln   = tid & 63;
    const int g    = ln >> 4;    // 0..3
    const int qi   = ln & 15;    // this lane's q row (score side) / d-local (PV out)

    const int bid   = blockIdx.x;
    const int b     = bid >> 5;          // 32 q-tiles per batch
    const int qt    = bid & 31;
    const int qbase = qt * QT;
    const int qrow  = qbase + wave * 16 + qi;

    const bool maskByte = (g_maskflag != 0);

    // ---- Q fragments: scaled, split hi/lo. B-operand layout: col=lane&15=q, k=(lane>>4)*8+j ----
    s16x8 qh8[4], ql8[4];
    {
        const float* qp = Q + ((size_t)b * NLQ + qrow) * ND;
        #pragma unroll
        for (int c = 0; c < 4; ++c) {
            const float* p = qp + c * 32 + g * 8;
            float4 x0 = *(const float4*)(p);
            float4 x1 = *(const float4*)(p + 4);
            s16x8 h, l;
            SPLIT8(h, l, 0, x0.x * SCALE); SPLIT8(h, l, 1, x0.y * SCALE);
            SPLIT8(h, l, 2, x0.z * SCALE); SPLIT8(h, l, 3, x0.w * SCALE);
            SPLIT8(h, l, 4, x1.x * SCALE); SPLIT8(h, l, 5, x1.y * SCALE);
            SPLIT8(h, l, 6, x1.z * SCALE); SPLIT8(h, l, 7, x1.w * SCALE);
            qh8[c] = h; ql8[c] = l;
        }
    }

    f32x4 o[8];
    #pragma unroll
    for (int t = 0; t < 8; ++t) o[t] = (f32x4){0.f, 0.f, 0.f, 0.f};
    float m_run = -INFINITY, lsum = 0.f;

    const float* kbp = K + (size_t)b * NLK * ND;
    const float* vbp = V + (size_t)b * NLK * ND;
    const size_t mrow = ((size_t)b * NLQ + qrow) * (size_t)NLK;

    for (int kt = 0; kt < NLK / KT; ++kt) {
        const int kb = kt * KT;
        __syncthreads();

        // ---- stage K tile as hi/lo bf16, swizzled [k][d] ----
        #pragma unroll
        for (int r = 0; r < 8; ++r) {
            int idx = r * 256 + tid;          // 0..2047
            int kk  = idx >> 5;               // 0..63
            int d0  = (idx & 31) << 2;        // 0..124
            float4 x = *(const float4*)(kbp + (size_t)(kb + kk) * ND + d0);
            ushort4 h4, l4; unsigned short hb;
            hb = f2bf(x.x); h4.x = hb; l4.x = f2bf(x.x - bf2f(hb));
            hb = f2bf(x.y); h4.y = hb; l4.y = f2bf(x.y - bf2f(hb));
            hb = f2bf(x.z); h4.z = hb; l4.z = f2bf(x.z - bf2f(hb));
            hb = f2bf(x.w); h4.w = hb; l4.w = f2bf(x.w - bf2f(hb));
            int off = (kk * ND + d0) ^ ((kk & 7) << 3);   // ushort units
            *(ushort4*)&sKh[off] = h4;
            *(ushort4*)&sKl[off] = l4;
        }
        // ---- stage V tile transposed bf16, swizzled [d][k] (4x4 micro-transpose) ----
        #pragma unroll
        for (int r = 0; r < 2; ++r) {
            int idx = r * 256 + tid;          // 0..511
            int kk0 = (idx >> 5) << 2;        // 0..60
            int d0  = (idx & 31) << 2;        // 0..124
            const float* vp = vbp + (size_t)(kb + kk0) * ND + d0;
            float4 r0 = *(const float4*)(vp);
            float4 r1 = *(const float4*)(vp + ND);
            float4 r2 = *(const float4*)(vp + 2 * ND);
            float4 r3 = *(const float4*)(vp + 3 * ND);
            ushort4 cv;
            cv.x = f2bf(r0.x); cv.y = f2bf(r1.x); cv.z = f2bf(r2.x); cv.w = f2bf(r3.x);
            { int d = d0;     *(ushort4*)&sVt[(d * KT + kk0) ^ ((d & 7) << 3)] = cv; }
            cv.x = f2bf(r0.y); cv.y = f2bf(r1.y); cv.z = f2bf(r2.y); cv.w = f2bf(r3.y);
            { int d = d0 + 1; *(ushort4*)&sVt[(d * KT + kk0) ^ ((d & 7) << 3)] = cv; }
            cv.x = f2bf(r0.z); cv.y = f2bf(r1.z); cv.z = f2bf(r2.z); cv.w = f2bf(r3.z);
            { int d = d0 + 2; *(ushort4*)&sVt[(d * KT + kk0) ^ ((d & 7) << 3)] = cv; }
            cv.x = f2bf(r0.w); cv.y = f2bf(r1.w); cv.z = f2bf(r2.w); cv.w = f2bf(r3.w);
            { int d = d0 + 3; *(ushort4*)&sVt[(d * KT + kk0) ^ ((d & 7) << 3)] = cv; }
        }
        __syncthreads();

        // ---- mask bits for this lane's 16 scores: k = kb + s*16 + 4g + j ----
        unsigned maskbits = 0;
        if (maskByte) {
            #pragma unroll
            for (int s = 0; s < 4; ++s) {
                unsigned mm = *(const unsigned int*)(Mb + mrow + (size_t)(kb + s * 16 + 4 * g));
                #pragma unroll
                for (int j = 0; j < 4; ++j)
                    maskbits |= (((mm >> (8 * j)) & 0xFFu) ? 1u : 0u) << (s * 4 + j);
            }
        } else {
            const int* Mi = (const int*)Mb;
            #pragma unroll
            for (int s = 0; s < 4; ++s) {
                int4 mm = *(const int4*)(Mi + mrow + (size_t)(kb + s * 16 + 4 * g));
                if (mm.x) maskbits |= 1u << (s * 4 + 0);
                if (mm.y) maskbits |= 1u << (s * 4 + 1);
                if (mm.z) maskbits |= 1u << (s * 4 + 2);
                if (mm.w) maskbits |= 1u << (s * 4 + 3);
            }
        }

        // ---- QK^T via 3-pass split MFMA: lane holds S[q=qi][k = kb+s*16+4g+j] ----
        float p[16];
        #pragma unroll
        for (int s = 0; s < 4; ++s) {
            f32x4 acc = (f32x4){0.f, 0.f, 0.f, 0.f};
            int rowoff = (s * 16 + qi) * ND;
            int swz = ((s * 16 + qi) & 7) << 3;
            #pragma unroll
            for (int c = 0; c < 4; ++c) {
                int off = (rowoff + c * 32 + g * 8) ^ swz;
                s16x8 kh = *(s16x8*)&sKh[off];
                s16x8 kl = *(s16x8*)&sKl[off];
                acc = __builtin_amdgcn_mfma_f32_16x16x32_bf16(kh, qh8[c], acc, 0, 0, 0);
                acc = __builtin_amdgcn_mfma_f32_16x16x32_bf16(kh, ql8[c], acc, 0, 0, 0);
                acc = __builtin_amdgcn_mfma_f32_16x16x32_bf16(kl, qh8[c], acc, 0, 0, 0);
            }
            p[s * 4 + 0] = acc[0]; p[s * 4 + 1] = acc[1];
            p[s * 4 + 2] = acc[2]; p[s * 4 + 3] = acc[3];
        }

        // ---- online softmax (row state replicated across lanes {qi, qi+16, qi+32, qi+48}) ----
        float tmax = -INFINITY;
        #pragma unroll
        for (int i = 0; i < 16; ++i) {
            float sv = ((maskbits >> i) & 1u) ? -INFINITY : p[i];
            p[i] = sv;
            tmax = fmaxf(tmax, sv);
        }
        tmax = fmaxf(tmax, __shfl_xor(tmax, 16));
        tmax = fmaxf(tmax, __shfl_xor(tmax, 32));
        float mnew = fmaxf(m_run, tmax);
        float corr = (mnew == -INFINITY) ? 0.f : __expf(m_run - mnew);
        float psum = 0.f;
        #pragma unroll
        for (int i = 0; i < 16; ++i) {
            float pv = ((maskbits >> i) & 1u) ? 0.f : __expf(p[i] - mnew);
            p[i] = pv;
            psum += pv;
        }
        psum += __shfl_xor(psum, 16);
        psum += __shfl_xor(psum, 32);
        lsum = lsum * corr + psum;
        m_run = mnew;

        // ---- rescale O (O rows are q=4g+j; corr lives at lane 4g+j) ----
        #pragma unroll
        for (int j = 0; j < 4; ++j) {
            float cj = __shfl(corr, 4 * g + j, 64);
            #pragma unroll
            for (int t = 0; t < 8; ++t) o[t][j] *= cj;
        }

        // ---- P -> LDS (bf16, swizzled [q][k]), then PV MFMA ----
        #pragma unroll
        for (int s = 0; s < 4; ++s) {
            ushort4 p4;
            p4.x = f2bf(p[s * 4 + 0]); p4.y = f2bf(p[s * 4 + 1]);
            p4.z = f2bf(p[s * 4 + 2]); p4.w = f2bf(p[s * 4 + 3]);
            int off = (qi * KT + s * 16 + 4 * g) ^ ((qi & 7) << 3);
            *(ushort4*)&sP[wave][off] = p4;
        }
        #pragma unroll
        for (int h = 0; h < 2; ++h) {
            int offp = (qi * KT + h * 32 + g * 8) ^ ((qi & 7) << 3);
            s16x8 pa = *(s16x8*)&sP[wave][offp];
            #pragma unroll
            for (int t = 0; t < 8; ++t) {
                int d = t * 16 + qi;
                int offv = (d * KT + h * 32 + g * 8) ^ ((d & 7) << 3);
                s16x8 vb = *(s16x8*)&sVt[offv];
                o[t] = __builtin_amdgcn_mfma_f32_16x16x32_bf16(pa, vb, o[t], 0, 0, 0);
            }
        }
    }

    // ---- epilogue: out = acc / l ; fully-masked rows (l==0) -> 0 (NaN->0 semantics) ----
    #pragma unroll
    for (int j = 0; j < 4; ++j) {
        float lj = __shfl(lsum, 4 * g + j, 64);
        float inv = (lj > 0.f) ? (1.0f / lj) : 0.f;
        int row = qbase + wave * 16 + 4 * g + j;
        float* op = Out + ((size_t)b * NLQ + row) * ND + qi;
        #pragma unroll
        for (int t = 0; t < 8; ++t) op[t * 16] = o[t][j] * inv;
    }
}

extern "C" void kernel_launch(void* const* d_in, const int* in_sizes, int n_in,
                              void* d_out, int out_size, void* d_ws, size_t ws_size,
                              hipStream_t stream) {
    (void)in_sizes; (void)n_in; (void)d_ws; (void)ws_size; (void)out_size;
    const float* Q = (const float*)d_in[0];
    const float* K = (const float*)d_in[1];
    const float* V = (const float*)d_in[2];
    const unsigned char* M = (const unsigned char*)d_in[3];
    float* Out = (float*)d_out;

    zero_flag_kernel<<<1, 64, 0, stream>>>();
    detect_mask_kernel<<<1024, 256, 0, stream>>>(M);
    attn_kernel<<<dim3(NB * (NLQ / QT)), dim3(256), 0, stream>>>(Q, K, V, M, Out);
}